// Round 15
// baseline (155.635 us; speedup 1.0000x reference)
//
#include <hip/hip_runtime.h>
#include <hip/hip_bf16.h>
#include <math.h>

// Problem constants (fixed by reference setup_inputs)
constexpr int NROWS = 8192;   // B
constexpr int HDIM  = 256;    // H (= K of the GEMM); also bytes/row in fp8
constexpr int N2    = 16384;  // 2*B rows of Z
constexpr int TM    = 256;    // tile M = tile N; 16 waves of 64x64 out each
constexpr int TILEB = TM * HDIM;      // 64 KB per fp8 tile (A or B)
constexpr int NTILE = N2 / TM;        // 64 tile-rows
constexpr int NBLK  = NTILE * (NTILE + 1) / 2;  // 2080 upper-tri tiles
constexpr int NPERS = 256;            // persistent blocks (1 per CU)

// sqrt(2 * log2(e)): Z pre-scaled so Zs_i.Zs_j = 2*log2(e)*cos and
// exp2(acc) == exp(sim/tau), tau = 0.5
constexpr float PRESCALE = 1.69864357f;

typedef __attribute__((ext_vector_type(4))) float floatx4;
typedef __attribute__((ext_vector_type(2))) long longx2;   // 16B LDS read

__device__ __forceinline__ void async_copy16(const void* gptr, void* lptr) {
    __builtin_amdgcn_global_load_lds(
        (const __attribute__((address_space(1))) unsigned int*)gptr,
        (__attribute__((address_space(3))) unsigned int*)lptr, 16, 0, 0);
}

// s_waitcnt immediates (gfx9: vm[3:0], exp[6:4], lgkm[11:8], vm-hi[15:14])
#define WAIT_VM0()   __builtin_amdgcn_s_waitcnt(0x0F70)  // vmcnt(0)
#define MEMFENCE()   __asm__ __volatile__("" ::: "memory")
#define RAW_BARRIER() do { MEMFENCE(); __builtin_amdgcn_s_barrier(); MEMFENCE(); } while (0)

// DPP row_shl add: VALU pipe, not DS (R9: -18us vs ds_bpermute shuffles).
#define DPP_ROW_SHL_ADD(v, CTRL) do {                                        \
    union { float f; int i; } _u, _r; _u.f = (v);                            \
    _r.i = __builtin_amdgcn_update_dpp(0, _u.i, (CTRL), 0xF, 0xF, true);     \
    (v) += _r.f; } while (0)

// Manual RNE float -> OCP e4m3fn (1-4-3, bias 7, subnormals m*2^-9).
// [R17-verified: absmax 0.0]
__device__ __forceinline__ unsigned int f32_to_e4m3(float f) {
    const float a = fabsf(f);
    const unsigned int s = f < 0.f ? 0x80u : 0u;
    if (a < 0.015625f) {                       // subnormal: m = rne(a*512)
        int mm = (int)rintf(a * 512.0f);       // 0..8
        if (mm == 8) return s | 0x08u;         // rounds up to 2^-6
        return s | (unsigned int)mm;
    }
    int e; const float fr = frexpf(a, &e);     // a = fr*2^e, fr in [0.5,1)
    int mm = (int)rintf(fr * 16.0f) - 8;       // 0..8
    int E  = e + 6;                            // biased exponent
    if (mm == 8) { mm = 0; E += 1; }
    if (E > 15) { E = 15; mm = 6; }            // clamp to 448 (never hit)
    return s | (unsigned int)((E << 3) | mm);
}

// Upper-triangle tile map (R21-verified): tile id b -> (bi,bj), XCD-local.
__device__ __forceinline__ void tile_map(int b, int& bi, int& bj) {
    const int k = b & 7;
    const int m = b >> 3;
    if (m < 36) {
        int ti = (int)((17.0f - sqrtf(289.0f - 8.0f * (float)m)) * 0.5f);
        if (m < ti * (17 - ti) / 2) ti--;
        else if (m >= (ti + 1) * (16 - ti) / 2) ti++;
        const int tj = ti + (m - ti * (17 - ti) / 2);
        bi = k * 8 + ti;
        bj = k * 8 + tj;
    } else {
        const int m2 = m - 36;           // 0..223
        const int hh = m2 >> 5;          // 0..6
        const int r  = m2 & 31;          // 0..31
        const int h  = hh * 8 + k;       // 0..55
        const int q  = h >> 1;           // 0..27
        const int sub = h & 1;
        int gi = 0;
        #pragma unroll
        for (int t = 6; t > 0; --t)
            if (q >= t * (15 - t) / 2) { gi = t; break; }
        const int gj = gi + 1 + (q - gi * (15 - gi) / 2);
        bi = gi * 8 + sub * 4 + (r >> 3);
        bj = gj * 8 + (r & 7);
    }
}

// ---------------------------------------------------------------------------
// Kernel 1: wave-per-row L2-normalize -> FP8 e4m3 Z, stored in sigma-permuted
// k-order (see kernel 2). pos = cos(x,y) exact fp32. [R21 verbatim]
// sigma: k = t*32 + g*8 + j -> pos = (t>>1)*64 + g*16 + (t&1)*8 + j.
// Lane holds k = lane*4..+3 -> 4 consecutive sigma-positions, one uint store.
// k-permutation harmless: A and B both read Z, dots are k-order invariant.
// ---------------------------------------------------------------------------
__global__ __launch_bounds__(256) void normalize_kernel(
    const float* __restrict__ x, const float* __restrict__ y,
    unsigned char* __restrict__ Zb, float* __restrict__ pos,
    float* __restrict__ rowsum, float* __restrict__ out)
{
    const int wave = threadIdx.x >> 6, lane = threadIdx.x & 63;
    const int row  = blockIdx.x * 4 + wave;           // grid 2048 -> 8192 rows

    const float4 xv = ((const float4*)x)[row * 64 + lane];
    const float4 yv = ((const float4*)y)[row * 64 + lane];

    float sx  = xv.x*xv.x + xv.y*xv.y + xv.z*xv.z + xv.w*xv.w;
    float sy  = yv.x*yv.x + yv.y*yv.y + yv.z*yv.z + yv.w*yv.w;
    float sxy = xv.x*yv.x + xv.y*yv.y + xv.z*yv.z + xv.w*yv.w;
    #pragma unroll
    for (int m = 1; m < 64; m <<= 1) {
        sx  += __shfl_xor(sx,  m);
        sy  += __shfl_xor(sy,  m);
        sxy += __shfl_xor(sxy, m);
    }
    const float rxn = rsqrtf(sx), ryn = rsqrtf(sy);
    const float rx = rxn * PRESCALE, ry = ryn * PRESCALE;

    const unsigned int px =
        f32_to_e4m3(xv.x * rx)        | (f32_to_e4m3(xv.y * rx) << 8) |
        (f32_to_e4m3(xv.z * rx) << 16) | (f32_to_e4m3(xv.w * rx) << 24);
    const unsigned int py =
        f32_to_e4m3(yv.x * ry)        | (f32_to_e4m3(yv.y * ry) << 8) |
        (f32_to_e4m3(yv.z * ry) << 16) | (f32_to_e4m3(yv.w * ry) << 24);

    // sigma-permuted destination (4B aligned, same 256B segment per wave)
    const int t  = lane >> 3;
    const int gg = (lane >> 1) & 3;
    const int posb = (t >> 1) * 64 + gg * 16 + (t & 1) * 8 + (lane & 1) * 4;

    *(unsigned int*)(Zb + (size_t)row * HDIM + posb)           = px;
    *(unsigned int*)(Zb + (size_t)(row + NROWS) * HDIM + posb) = py;

    if (lane == 0) {
        const float p = sxy * rxn * ryn;   // exact fp32 numerator path
        pos[row]         = p;
        pos[row + NROWS] = p;
    }
    const int gt = blockIdx.x * 256 + threadIdx.x;
    if (gt < N2) rowsum[gt] = 0.f;
    if (gt == 0) out[0] = 0.f;
}

// ---------------------------------------------------------------------------
// Kernel 2: upper-triangle tiled Z·Z^T (FP8), fused exp2 + row/col sums.
// R22: PERSISTENT BLOCKS + PREFETCH-UNDER-EPILOGUE on the R21 chassis
// (single-shot whole-K, sigma layout, conflict-free b128 frag reads — all
// verbatim, absmax 0.0). R21 accounting (25.8k cyc/tile/CU): MFMA ~10k,
// epilogue ~5k, prologue stage+vm0+barrier ~2.5-3k FULLY EXPOSED (at 1
// block/CU a retiring block's epilogue and the next block's prologue
// cannot overlap). Fix: grid 256 (1 persistent block/CU); block walks
// tiles b = blockIdx.x + 256*t (k=b&7 invariant -> XCD affinity kept; all
// 2080 tiles covered once; blocks 0-31 do 9 tiles, rest 8 = same 8.125
// tail as before). Per tile:
//   K-loop (barrier-free) -> BARRIER (all LDS reads done) ->
//   STAGE(next tile) into the now-dead LDS (async) ->
//   epilogue (~5k cyc; covers ~2.5k load latency) ->
//   rowsum atomics; rs/cs re-zero (own-entry only, hazard-free) ->
//   WAIT_VM0 + BARRIER -> next K-loop.
// WAR: stage writes start only after the post-K barrier (all waves done
// reading). RAW: vm0 (own 8 copies + epilogue atomics) + barrier before
// next K-loop. rs/cs: tid reads/zeroes only rs[tid]; >=2 barriers separate
// the zero from the next tile's epilogue atomics.
// ---------------------------------------------------------------------------
__global__ __launch_bounds__(1024, 4) void simgemm_kernel(
    const unsigned char* __restrict__ Zb, float* __restrict__ rowsum)
{
    // LDS: A tile 64KB | B tile 64KB | rs/cs 2KB = 130KB (1 block/CU)
    __shared__ alignas(16) unsigned char tiles[2 * TILEB];  // 128 KB
    __shared__ float rs[TM];
    __shared__ float cs[TM];

    const int tid  = threadIdx.x;
    const int wave = tid >> 6;            // 0..15
    const int lane = tid & 63;
    const int wm   = wave & 3;            // wave row band: rows wm*64..+64
    const int wn   = wave >> 2;           // wave col band: cols wn*64..+64
    const int g    = lane >> 4;           // quad (0..3)
    const int m15  = lane & 15;

    if (tid < TM) { rs[tid] = 0.f; cs[tid] = 0.f; }

    // ---- tile-invariant staging lane constants (R21 verbatim) ----
    const int rl4 = lane >> 4;                    // row within 4-row copy
    const int se  = ((lane & 15) ^ rl4) * 16;           // c even source off
    const int so  = (((lane & 15) ^ rl4) ^ 4) * 16;     // c odd  source off
    unsigned char* lA = tiles + (wave * 16) * HDIM;          // + lane*16
    unsigned char* lB = tiles + TILEB + (wave * 16) * HDIM;

    // stage tile (BI,BJ): 8 async copies, wave w covers rows [w*16,+16)
    #define STAGE(BI, BJ) do {                                               \
        const unsigned char* _gA =                                           \
            Zb + (size_t)((BI) * TM + wave * 16 + rl4) * HDIM;               \
        const unsigned char* _gB =                                           \
            Zb + (size_t)((BJ) * TM + wave * 16 + rl4) * HDIM;               \
        async_copy16(_gA + 0 * 1024 + se, lA + 0 * 1024);                    \
        async_copy16(_gA + 1 * 1024 + so, lA + 1 * 1024);                    \
        async_copy16(_gA + 2 * 1024 + se, lA + 2 * 1024);                    \
        async_copy16(_gA + 3 * 1024 + so, lA + 3 * 1024);                    \
        async_copy16(_gB + 0 * 1024 + se, lB + 0 * 1024);                    \
        async_copy16(_gB + 1 * 1024 + so, lB + 1 * 1024);                    \
        async_copy16(_gB + 2 * 1024 + se, lB + 2 * 1024);                    \
        async_copy16(_gB + 3 * 1024 + so, lB + 3 * 1024);                    \
    } while (0)

    // ---- fragment read bases (tile-invariant) ----
    const int key  = m15 & 7;
    const int rowA = (wm * 64 + m15) * HDIM;
    const int rowB = (wn * 64 + m15) * HDIM;
    const unsigned char* bA = tiles;
    const unsigned char* bB = tiles + TILEB;

    // ---- first tile prologue ----
    int b = blockIdx.x;                   // current tile id (< 256 <= NBLK)
    int bi, bj;
    tile_map(b, bi, bj);
    STAGE(bi, bj);
    WAIT_VM0();
    RAW_BARRIER();     // tile-b data landed; LDS read-only until post-K bar

    for (;;) {
        // ---- barrier-free K-loop: 4 kstep-pairs x (8 b128 + 32 MFMA) ----
        floatx4 acc[4][4] = {};
        #pragma unroll
        for (int u = 0; u < 4; ++u) {
            const int off = ((u * 4 + g) ^ key) * 16;   // conflict-free
            longx2 aV[4], bV[4];
            #pragma unroll
            for (int f = 0; f < 4; ++f) {
                aV[f] = *(const longx2*)(bA + rowA + f * 16 * HDIM + off);
                bV[f] = *(const longx2*)(bB + rowB + f * 16 * HDIM + off);
            }
            #pragma unroll
            for (int ks = 0; ks < 2; ++ks)
                #pragma unroll
                for (int fm = 0; fm < 4; ++fm)
                    #pragma unroll
                    for (int fn = 0; fn < 4; ++fn)
                        acc[fm][fn] = __builtin_amdgcn_mfma_f32_16x16x32_fp8_fp8(
                            aV[fm][ks], bV[fn][ks], acc[fm][fn], 0, 0, 0);
        }

        RAW_BARRIER();   // ALL waves done reading tile-b LDS

        // ---- prefetch next tile into the now-dead LDS (hidden by epilogue)
        const int bnext = b + NPERS;
        const bool have_next = bnext < NBLK;
        int bi2 = 0, bj2 = 0;
        if (have_next) {
            tile_map(bnext, bi2, bj2);
            STAGE(bi2, bj2);
        }

        // ---- epilogue: e = exp2(acc), reduce rows & cols ----
        const bool diag = (bi == bj);
        float rp[4][4] = {{0.f}};
        float cp[4]    = {0.f};

        if (!diag) {
            #pragma unroll
            for (int fm = 0; fm < 4; ++fm)
                #pragma unroll
                for (int fn = 0; fn < 4; ++fn) {
                    const floatx4 a = acc[fm][fn];
                    #pragma unroll
                    for (int q = 0; q < 4; ++q) {
                        const float e = __builtin_amdgcn_exp2f(a[q]);
                        rp[fm][q] += e;
                        cp[fn]    += e;
                    }
                }
        } else {
            #pragma unroll
            for (int fm = 0; fm < 4; ++fm)
                #pragma unroll
                for (int fn = 0; fn < 4; ++fn) {
                    const floatx4 a = acc[fm][fn];
                    const int cl = wn * 64 + fn * 16 + m15;
                    #pragma unroll
                    for (int q = 0; q < 4; ++q) {
                        const int rl = wm * 64 + fm * 16 + g * 4 + q;
                        float e = __builtin_amdgcn_exp2f(a[q]);
                        if (cl <= rl) e = 0.f;   // strictly-upper only
                        rp[fm][q] += e;
                        cp[fn]    += e;
                    }
                }
        }

        // row sums: 16-lane DPP reduction; total lands in m15==0
        #pragma unroll
        for (int fm = 0; fm < 4; ++fm)
            #pragma unroll
            for (int q = 0; q < 4; ++q) {
                float v = rp[fm][q];
                DPP_ROW_SHL_ADD(v, 0x101);   // row_shl:1
                DPP_ROW_SHL_ADD(v, 0x102);   // row_shl:2
                DPP_ROW_SHL_ADD(v, 0x104);   // row_shl:4
                DPP_ROW_SHL_ADD(v, 0x108);   // row_shl:8
                rp[fm][q] = v;
            }
        if (m15 == 0) {
            #pragma unroll
            for (int fm = 0; fm < 4; ++fm)
                #pragma unroll
                for (int q = 0; q < 4; ++q)
                    atomicAdd(&rs[wm * 64 + fm * 16 + g * 4 + q], rp[fm][q]);
        }

        // col sums: reduce across quads
        #pragma unroll
        for (int mask = 16; mask < 64; mask <<= 1)
            #pragma unroll
            for (int fn = 0; fn < 4; ++fn)
                cp[fn] += __shfl_xor(cp[fn], mask);
        if (g == 0) {
            #pragma unroll
            for (int fn = 0; fn < 4; ++fn)
                atomicAdd(&cs[wn * 64 + fn * 16 + m15], cp[fn]);
        }

        __syncthreads();   // all rs/cs contributions in
        if (tid < TM) {
            atomicAdd(&rowsum[(size_t)bi * TM + tid], rs[tid]);
            atomicAdd(&rowsum[(size_t)bj * TM + tid], cs[tid]);
            rs[tid] = 0.f;   // own-entry only: no cross-thread hazard;
            cs[tid] = 0.f;   // >=2 barriers before next tile's atomics
        }

        if (!have_next) break;
        b = bnext; bi = bi2; bj = bj2;
        WAIT_VM0();        // next-tile stage (+ epilogue atomics) retired
        RAW_BARRIER();     // all waves' stage landed; LDS ready
    }
    #undef STAGE
}

// ---------------------------------------------------------------------------
// Kernel 3: loss = mean( log(rowsum_i) - 2*pos_i ), 16 blocks + atomic.
// ---------------------------------------------------------------------------
__global__ __launch_bounds__(1024) void finalize_kernel(
    const float* __restrict__ rowsum, const float* __restrict__ pos,
    float* __restrict__ out)
{
    const int i = threadIdx.x + blockIdx.x * 1024;
    float s = logf(rowsum[i]) - 2.0f * pos[i];
    #pragma unroll
    for (int off = 32; off; off >>= 1) s += __shfl_down(s, off);
    __shared__ float sh[16];
    const int lt = threadIdx.x;
    if ((lt & 63) == 0) sh[lt >> 6] = s;
    __syncthreads();
    if (lt == 0) {
        float tot = 0.f;
        #pragma unroll
        for (int w = 0; w < 16; ++w) tot += sh[w];
        atomicAdd(out, tot / (float)N2);
    }
}

// ---------------------------------------------------------------------------
extern "C" void kernel_launch(void* const* d_in, const int* in_sizes, int n_in,
                              void* d_out, int out_size, void* d_ws, size_t ws_size,
                              hipStream_t stream)
{
    const float* x = (const float*)d_in[0];
    const float* y = (const float*)d_in[1];

    // workspace: Z fp8 [16384*256] (4 MB) | rowsum f32 [16384] | pos f32 [16384]
    unsigned char* Zb = (unsigned char*)d_ws;
    float* rowsum = (float*)((char*)d_ws + (size_t)N2 * HDIM);
    float* pos    = rowsum + N2;

    normalize_kernel<<<NROWS / 4, 256, 0, stream>>>(x, y, Zb, pos, rowsum, (float*)d_out);
    simgemm_kernel<<<NPERS, 1024, 0, stream>>>(Zb, rowsum);
    finalize_kernel<<<N2 / 1024, 1024, 0, stream>>>(rowsum, pos, (float*)d_out);
}

// Round 17
// 154.854 us; speedup vs baseline: 1.0050x; 1.0050x over previous
//
#include <hip/hip_runtime.h>
#include <hip/hip_bf16.h>
#include <math.h>

// Problem constants (fixed by reference setup_inputs)
constexpr int NROWS = 8192;   // B
constexpr int HDIM  = 256;    // H (= K of the GEMM); also bytes/row in fp8
constexpr int N2    = 16384;  // 2*B rows of Z
constexpr int TM    = 128;    // tile M = tile N; 8 waves of 32x64 out each
constexpr int TILEB = TM * HDIM;      // 32 KB per fp8 tile (A or B)
constexpr int NTILE = N2 / TM;        // 128 tile-rows
constexpr int NBLK  = NTILE * (NTILE + 1) / 2;  // 8256 upper-tri tiles

// sqrt(2 * log2(e)): Z pre-scaled so Zs_i.Zs_j = 2*log2(e)*cos and
// exp2(acc) == exp(sim/tau), tau = 0.5
constexpr float PRESCALE = 1.69864357f;

typedef __attribute__((ext_vector_type(4))) float floatx4;
typedef __attribute__((ext_vector_type(2))) long longx2;   // 16B LDS read

__device__ __forceinline__ void async_copy16(const void* gptr, void* lptr) {
    __builtin_amdgcn_global_load_lds(
        (const __attribute__((address_space(1))) unsigned int*)gptr,
        (__attribute__((address_space(3))) unsigned int*)lptr, 16, 0, 0);
}

// s_waitcnt immediates (gfx9: vm[3:0], exp[6:4], lgkm[11:8], vm-hi[15:14])
#define WAIT_VM0()   __builtin_amdgcn_s_waitcnt(0x0F70)  // vmcnt(0)
#define MEMFENCE()   __asm__ __volatile__("" ::: "memory")
#define RAW_BARRIER() do { MEMFENCE(); __builtin_amdgcn_s_barrier(); MEMFENCE(); } while (0)

// DPP row_shl add: VALU pipe, not DS (R9: -18us vs ds_bpermute shuffles).
#define DPP_ROW_SHL_ADD(v, CTRL) do {                                        \
    union { float f; int i; } _u, _r; _u.f = (v);                            \
    _r.i = __builtin_amdgcn_update_dpp(0, _u.i, (CTRL), 0xF, 0xF, true);     \
    (v) += _r.f; } while (0)

// Manual RNE float -> OCP e4m3fn (1-4-3, bias 7, subnormals m*2^-9).
// [R17-verified: absmax 0.0]
__device__ __forceinline__ unsigned int f32_to_e4m3(float f) {
    const float a = fabsf(f);
    const unsigned int s = f < 0.f ? 0x80u : 0u;
    if (a < 0.015625f) {                       // subnormal: m = rne(a*512)
        int mm = (int)rintf(a * 512.0f);       // 0..8
        if (mm == 8) return s | 0x08u;         // rounds up to 2^-6
        return s | (unsigned int)mm;
    }
    int e; const float fr = frexpf(a, &e);     // a = fr*2^e, fr in [0.5,1)
    int mm = (int)rintf(fr * 16.0f) - 8;       // 0..8
    int E  = e + 6;                            // biased exponent
    if (mm == 8) { mm = 0; E += 1; }
    if (E > 15) { E = 15; mm = 6; }            // clamp to 448 (never hit)
    return s | (unsigned int)((E << 3) | mm);
}

// ---------------------------------------------------------------------------
// Kernel 1: wave-per-row L2-normalize -> FP8 e4m3 Z, stored in sigma-permuted
// k-order (see kernel 2). pos = cos(x,y) exact fp32. [R21 verbatim]
// sigma: k = t*32 + g*8 + j -> pos = (t>>1)*64 + g*16 + (t&1)*8 + j.
// Lane holds k = lane*4..+3 -> 4 consecutive sigma-positions, one uint store.
// k-permutation harmless: A and B both read Z, dots are k-order invariant.
// ---------------------------------------------------------------------------
__global__ __launch_bounds__(256) void normalize_kernel(
    const float* __restrict__ x, const float* __restrict__ y,
    unsigned char* __restrict__ Zb, float* __restrict__ pos,
    float* __restrict__ rowsum, float* __restrict__ out)
{
    const int wave = threadIdx.x >> 6, lane = threadIdx.x & 63;
    const int row  = blockIdx.x * 4 + wave;           // grid 2048 -> 8192 rows

    const float4 xv = ((const float4*)x)[row * 64 + lane];
    const float4 yv = ((const float4*)y)[row * 64 + lane];

    float sx  = xv.x*xv.x + xv.y*xv.y + xv.z*xv.z + xv.w*xv.w;
    float sy  = yv.x*yv.x + yv.y*yv.y + yv.z*yv.z + yv.w*yv.w;
    float sxy = xv.x*yv.x + xv.y*yv.y + xv.z*yv.z + xv.w*yv.w;
    #pragma unroll
    for (int m = 1; m < 64; m <<= 1) {
        sx  += __shfl_xor(sx,  m);
        sy  += __shfl_xor(sy,  m);
        sxy += __shfl_xor(sxy, m);
    }
    const float rxn = rsqrtf(sx), ryn = rsqrtf(sy);
    const float rx = rxn * PRESCALE, ry = ryn * PRESCALE;

    const unsigned int px =
        f32_to_e4m3(xv.x * rx)        | (f32_to_e4m3(xv.y * rx) << 8) |
        (f32_to_e4m3(xv.z * rx) << 16) | (f32_to_e4m3(xv.w * rx) << 24);
    const unsigned int py =
        f32_to_e4m3(yv.x * ry)        | (f32_to_e4m3(yv.y * ry) << 8) |
        (f32_to_e4m3(yv.z * ry) << 16) | (f32_to_e4m3(yv.w * ry) << 24);

    // sigma-permuted destination (4B aligned, same 256B segment per wave)
    const int t  = lane >> 3;
    const int gg = (lane >> 1) & 3;
    const int posb = (t >> 1) * 64 + gg * 16 + (t & 1) * 8 + (lane & 1) * 4;

    *(unsigned int*)(Zb + (size_t)row * HDIM + posb)           = px;
    *(unsigned int*)(Zb + (size_t)(row + NROWS) * HDIM + posb) = py;

    if (lane == 0) {
        const float p = sxy * rxn * ryn;   // exact fp32 numerator path
        pos[row]         = p;
        pos[row + NROWS] = p;
    }
    const int gt = blockIdx.x * 256 + threadIdx.x;
    if (gt < N2) rowsum[gt] = 0.f;
    if (gt == 0) out[0] = 0.f;
}

// ---------------------------------------------------------------------------
// Kernel 2: upper-triangle tiled Z·Z^T (FP8), fused exp2 + row/col sums.
// R23 (resubmitted after infra failure — audited: one vm0 + one
// unconditional barrier, no OOB, 65KB LDS, ~90 regs <= 128 at (512,4)):
// R21 chassis (single-shot whole-K, sigma layout, conflict-free b128 frag
// reads, one-shot blocks — all verbatim, absmax 0.0) at TM=128 with 512
// threads -> TWO INDEPENDENT blocks per CU.
// Post-R22 ledger: persistence regressed (post-K barrier skew + stride-256
// L2 loss); R21's exposed edges are the per-tile prologue/epilogue at 1
// block/CU and the 2080-on-256 tail (~10us). Fix both by halving the tile:
// A+B = 64KB LDS (+1KB rs/cs) -> 2 blocks/CU (130KB<=160KB); per-wave out
// 32x64 -> acc[2][4] = 32 regs, ~90 combined <= 128 -> (512,4) = 4
// waves/SIMD from 2 INDEPENDENT blocks (R19's goal without the m69
// register catastrophe). One block's epilogue/prologue overlaps the
// other's barrier-free K-loop (m114); 8256 blocks 2-deep -> tail ~2.7us.
// Geometry: 8 waves = 4 row-bands (wm, 32 rows) x 2 col-bands (wn, 64
// cols); acc[2][4] (fm 2x16 rows, fn 4x16 cols). Per u-iter: 6 b128 reads
// + 16 MFMA. Staging: wave w covers rows [w*16,+16) of A and B (A has 128
// rows = 8 waves) — R21 STAGE verbatim. Frag-read lane algebra
// (key = m15&7, off = ((u*4+g)^key)*16) is per-wave -> conflict-free
// property carries unchanged. Tile map: R0-era NTILE=128 XCD-local
// bijection (verified absmax 0.0 across R0-R9).
// WAR/RAW: LDS read-only after the single barrier — vanish by construction.
// ---------------------------------------------------------------------------
__global__ __launch_bounds__(512, 4) void simgemm_kernel(
    const unsigned char* __restrict__ Zb, float* __restrict__ rowsum)
{
    // ---- XCD-local block -> (bi,bj) mapping (bijection onto upper tri) ----
    // 8256 = 8 XCDs x 1032; per XCD: 136 diag-group tiles + 7 halves (8x16)
    const int b = blockIdx.x;
    const int k = b & 7;        // XCD under round-robin dispatch heuristic
    const int m = b >> 3;       // 0..1031 local rank within XCD
    int bi, bj;
    if (m < 136) {
        // diagonal group k: 16x16 upper triangle, cum(t) = t*(33-t)/2
        int ti = (int)((33.0f - sqrtf(1089.0f - 8.0f * (float)m)) * 0.5f);
        if (m < ti * (33 - ti) / 2) ti--;
        else if (m >= (ti + 1) * (32 - ti) / 2) ti++;
        const int tj = ti + (m - ti * (33 - ti) / 2);
        bi = k * 16 + ti;
        bj = k * 16 + tj;
    } else {
        const int m2 = m - 136;          // 0..895
        const int hh = m2 >> 7;          // 0..6  (which of my 7 halves)
        const int r  = m2 & 127;         // 0..127 within half (8x16 tiles)
        const int h  = hh * 8 + k;       // 0..55 global half index
        const int q  = h >> 1;           // 0..27 off-diag group pair
        const int sub = h & 1;
        int gi = 0;
        #pragma unroll
        for (int t = 6; t > 0; --t)
            if (q >= t * (15 - t) / 2) { gi = t; break; }
        const int gj = gi + 1 + (q - gi * (15 - gi) / 2);
        bi = gi * 16 + sub * 8 + (r >> 4);
        bj = gj * 16 + (r & 15);
    }
    const bool diag = (bi == bj);

    // LDS: A tile 32KB | B tile 32KB | rs/cs 1KB = 65KB -> 2 blocks/CU
    __shared__ alignas(16) unsigned char tiles[2 * TILEB];  // 64 KB
    __shared__ float rs[TM];
    __shared__ float cs[TM];

    const int tid  = threadIdx.x;
    const int wave = tid >> 6;            // 0..7
    const int lane = tid & 63;
    const int wm   = wave & 3;            // row band: rows wm*32..+32
    const int wn   = wave >> 2;           // col band: cols wn*64..+64
    const int g    = lane >> 4;           // quad (0..3)
    const int m15  = lane & 15;

    if (tid < TM) { rs[tid] = 0.f; cs[tid] = 0.f; }

    // ---- one-shot staging: wave w covers rows [w*16,+16) of A and B ----
    // [R21 verbatim] copy c = 4 rows; lane l -> row w*16+4c+(l>>4), phys
    // slot l&15 (dest linear = base+l*16), source slot = (l&15)^((4c+(l>>4))&7)
    const int rl4 = lane >> 4;                    // row within 4-row copy
    const int se  = ((lane & 15) ^ rl4) * 16;           // c even source off
    const int so  = (((lane & 15) ^ rl4) ^ 4) * 16;     // c odd  source off
    const unsigned char* gA = Zb + (size_t)(bi * TM + wave * 16 + rl4) * HDIM;
    const unsigned char* gB = Zb + (size_t)(bj * TM + wave * 16 + rl4) * HDIM;
    unsigned char* lA = tiles + (wave * 16) * HDIM;          // + lane*16
    unsigned char* lB = tiles + TILEB + (wave * 16) * HDIM;

    async_copy16(gA + 0 * 1024 + se, lA + 0 * 1024);
    async_copy16(gA + 1 * 1024 + so, lA + 1 * 1024);
    async_copy16(gA + 2 * 1024 + se, lA + 2 * 1024);
    async_copy16(gA + 3 * 1024 + so, lA + 3 * 1024);
    async_copy16(gB + 0 * 1024 + se, lB + 0 * 1024);
    async_copy16(gB + 1 * 1024 + so, lB + 1 * 1024);
    async_copy16(gB + 2 * 1024 + se, lB + 2 * 1024);
    async_copy16(gB + 3 * 1024 + so, lB + 3 * 1024);

    WAIT_VM0();        // own 8 copies retired
    RAW_BARRIER();     // all waves' copies landed; LDS read-only hereafter

    // ---- fragment read bases ----
    const int key  = m15 & 7;
    const int rowA = (wm * 32 + m15) * HDIM;     // + fm*16*HDIM, fm in {0,1}
    const int rowB = (wn * 64 + m15) * HDIM;     // + fn*16*HDIM, fn in 0..3
    const unsigned char* bA = tiles;
    const unsigned char* bB = tiles + TILEB;

    floatx4 acc[2][4] = {};

    // ---- barrier-free K-loop: 4 kstep-pairs x (6 b128 + 16 MFMA) ----
    #pragma unroll
    for (int u = 0; u < 4; ++u) {
        const int off = ((u * 4 + g) ^ key) * 16;   // conflict-free (R21)
        longx2 aV[2], bV[4];
        #pragma unroll
        for (int f = 0; f < 2; ++f)
            aV[f] = *(const longx2*)(bA + rowA + f * 16 * HDIM + off);
        #pragma unroll
        for (int f = 0; f < 4; ++f)
            bV[f] = *(const longx2*)(bB + rowB + f * 16 * HDIM + off);
        #pragma unroll
        for (int ks = 0; ks < 2; ++ks)
            #pragma unroll
            for (int fm = 0; fm < 2; ++fm)
                #pragma unroll
                for (int fn = 0; fn < 4; ++fn)
                    acc[fm][fn] = __builtin_amdgcn_mfma_f32_16x16x32_fp8_fp8(
                        aV[fm][ks], bV[fn][ks], acc[fm][fn], 0, 0, 0);
    }

    // ---- epilogue: e = exp2(acc) (== exp(sim/tau)), reduce rows & cols ----
    float rp[2][4] = {{0.f}};  // [fm][reg] partial row sums
    float cp[4]    = {0.f};    // [fn]      partial col sums

    if (!diag) {
        #pragma unroll
        for (int fm = 0; fm < 2; ++fm)
            #pragma unroll
            for (int fn = 0; fn < 4; ++fn) {
                const floatx4 a = acc[fm][fn];
                #pragma unroll
                for (int q = 0; q < 4; ++q) {
                    const float e = __builtin_amdgcn_exp2f(a[q]);
                    rp[fm][q] += e;
                    cp[fn]    += e;
                }
            }
    } else {
        #pragma unroll
        for (int fm = 0; fm < 2; ++fm)
            #pragma unroll
            for (int fn = 0; fn < 4; ++fn) {
                const floatx4 a = acc[fm][fn];
                const int cl = wn * 64 + fn * 16 + m15;
                #pragma unroll
                for (int q = 0; q < 4; ++q) {
                    const int rl = wm * 32 + fm * 16 + g * 4 + q;
                    float e = __builtin_amdgcn_exp2f(a[q]);
                    if (cl <= rl) e = 0.f;   // strictly-upper only
                    rp[fm][q] += e;
                    cp[fn]    += e;
                }
            }
    }

    // row sums: 16-lane DPP reduction (VALU pipe); total lands in m15==0
    #pragma unroll
    for (int fm = 0; fm < 2; ++fm)
        #pragma unroll
        for (int q = 0; q < 4; ++q) {
            float v = rp[fm][q];
            DPP_ROW_SHL_ADD(v, 0x101);   // row_shl:1
            DPP_ROW_SHL_ADD(v, 0x102);   // row_shl:2
            DPP_ROW_SHL_ADD(v, 0x104);   // row_shl:4
            DPP_ROW_SHL_ADD(v, 0x108);   // row_shl:8
            rp[fm][q] = v;
        }
    if (m15 == 0) {
        #pragma unroll
        for (int fm = 0; fm < 2; ++fm)
            #pragma unroll
            for (int q = 0; q < 4; ++q)
                atomicAdd(&rs[wm * 32 + fm * 16 + g * 4 + q], rp[fm][q]);
    }

    // col sums: reduce across quads
    #pragma unroll
    for (int mask = 16; mask < 64; mask <<= 1)
        #pragma unroll
        for (int fn = 0; fn < 4; ++fn)
            cp[fn] += __shfl_xor(cp[fn], mask);
    if (g == 0) {
        #pragma unroll
        for (int fn = 0; fn < 4; ++fn)
            atomicAdd(&cs[wn * 64 + fn * 16 + m15], cp[fn]);
    }

    __syncthreads();
    if (tid < TM) {
        atomicAdd(&rowsum[(size_t)bi * TM + tid], rs[tid]);
        atomicAdd(&rowsum[(size_t)bj * TM + tid], cs[tid]);
    }
}

// ---------------------------------------------------------------------------
// Kernel 3: loss = mean( log(rowsum_i) - 2*pos_i ), 16 blocks + atomic.
// ---------------------------------------------------------------------------
__global__ __launch_bounds__(1024) void finalize_kernel(
    const float* __restrict__ rowsum, const float* __restrict__ pos,
    float* __restrict__ out)
{
    const int i = threadIdx.x + blockIdx.x * 1024;
    float s = logf(rowsum[i]) - 2.0f * pos[i];
    #pragma unroll
    for (int off = 32; off; off >>= 1) s += __shfl_down(s, off);
    __shared__ float sh[16];
    const int lt = threadIdx.x;
    if ((lt & 63) == 0) sh[lt >> 6] = s;
    __syncthreads();
    if (lt == 0) {
        float tot = 0.f;
        #pragma unroll
        for (int w = 0; w < 16; ++w) tot += sh[w];
        atomicAdd(out, tot / (float)N2);
    }
}

// ---------------------------------------------------------------------------
extern "C" void kernel_launch(void* const* d_in, const int* in_sizes, int n_in,
                              void* d_out, int out_size, void* d_ws, size_t ws_size,
                              hipStream_t stream)
{
    const float* x = (const float*)d_in[0];
    const float* y = (const float*)d_in[1];

    // workspace: Z fp8 [16384*256] (4 MB) | rowsum f32 [16384] | pos f32 [16384]
    unsigned char* Zb = (unsigned char*)d_ws;
    float* rowsum = (float*)((char*)d_ws + (size_t)N2 * HDIM);
    float* pos    = rowsum + N2;

    normalize_kernel<<<NROWS / 4, 256, 0, stream>>>(x, y, Zb, pos, rowsum, (float*)d_out);
    simgemm_kernel<<<NBLK, 512, 0, stream>>>(Zb, rowsum);
    finalize_kernel<<<N2 / 1024, 1024, 0, stream>>>(rowsum, pos, (float*)d_out);
}